// Round 5
// baseline (1090.538 us; speedup 1.0000x reference)
//
#include <hip/hip_runtime.h>
#include <hip/hip_bf16.h>

#define N_NODES 50000
#define N_EDGES 800000
#define DIM 128
#define HID 256
#define N_GRAPH 512
#define N_LAYER 3
#define EFEAT 8
#define BN_EPS 1e-5f

typedef unsigned short u16;
typedef unsigned int u32;

using bf16x8_t = short __attribute__((ext_vector_type(8)));
using f32x4_t  = float __attribute__((ext_vector_type(4)));

// ---------------------------------------------------------------- utilities
__device__ __forceinline__ void atomic_add_f(float* p, float v) { unsafeAtomicAdd(p, v); }
__device__ __forceinline__ u16 f2bf(float x) {
    union { float f; u32 u; } v; v.f = x;
    u32 r = v.u + 0x7FFF + ((v.u >> 16) & 1);
    return (u16)(r >> 16);
}
__device__ __forceinline__ float bf2f(u16 u) {
    union { u32 i; float f; } v; v.i = (u32)u << 16; return v.f;
}
__device__ __forceinline__ float2 up2(u32 p) {
    return make_float2(bf2f((u16)(p & 0xFFFF)), bf2f((u16)(p >> 16)));
}
__device__ __forceinline__ u32 pk2(float a, float b) {
    return (u32)f2bf(a) | ((u32)f2bf(b) << 16);
}
__device__ __forceinline__ u32 ld32(const u16* base, u32 boff) {
    return *(const u32*)((const char*)base + boff);
}
__device__ __forceinline__ uint4 ld128(const u16* base, u32 boff) {
    return *(const uint4*)((const char*)base + boff);
}

// ---------------------------------------------------------------- weight transpose+convert to bf16
__global__ __launch_bounds__(256) void wconv_kernel(
    const float* __restrict__ W1, const float* __restrict__ W2,
    u16* __restrict__ W1t, u16* __restrict__ W2t)
{
    int idx = blockIdx.x * 256 + threadIdx.x;
    if (idx >= 6 * 32768) return;
    int m = idx >> 15;
    int off = idx & 32767;
    int l = m >> 1;
    if ((m & 1) == 0) {
        int r = off >> 8, c = off & 255;
        W1t[(size_t)l * 32768 + c * 128 + r] = f2bf(W1[(size_t)l * 32768 + r * 256 + c]);
    } else {
        int r = off >> 7, c = off & 127;
        W2t[(size_t)l * 32768 + c * 256 + r] = f2bf(W2[(size_t)l * 32768 + r * 128 + c]);
    }
}

// ---------------------------------------------------------------- edge_attr -> bf16 (once)
__global__ __launch_bounds__(256) void eaconv_kernel(const float* __restrict__ ea, u16* __restrict__ eab) {
    int e = blockIdx.x * 256 + threadIdx.x;
    if (e >= N_EDGES) return;
    const float4 lo = *(const float4*)(ea + (size_t)e * EFEAT);
    const float4 hi = *(const float4*)(ea + (size_t)e * EFEAT + 4);
    uint4 q;
    q.x = pk2(lo.x, lo.y); q.y = pk2(lo.z, lo.w);
    q.z = pk2(hi.x, hi.y); q.w = pk2(hi.z, hi.w);
    *(uint4*)(eab + (size_t)e * EFEAT) = q;
}

// ---------------------------------------------------------------- CSR build
__global__ __launch_bounds__(256) void hist_kernel(const int* __restrict__ ei, int* __restrict__ deg) {
    int e = blockIdx.x * 256 + threadIdx.x;
    if (e < N_EDGES) atomicAdd(&deg[ei[N_EDGES + e]], 1);
}

// exclusive scan deg -> rowptr, then zero deg (reused as cursor by scatter)
__global__ __launch_bounds__(1024) void scan_kernel(int* __restrict__ deg, int* __restrict__ rowptr) {
    __shared__ int wsum[16];
    __shared__ int carry;
    int tid = threadIdx.x;
    if (tid == 0) { carry = 0; rowptr[0] = 0; }
    __syncthreads();
    for (int base = 0; base < N_NODES; base += 1024) {
        int i = base + tid;
        int v = (i < N_NODES) ? deg[i] : 0;
        int lane = tid & 63, w = tid >> 6;
        int s = v;
        #pragma unroll
        for (int d = 1; d < 64; d <<= 1) { int t = __shfl_up(s, d); if (lane >= d) s += t; }
        if (lane == 63) wsum[w] = s;
        __syncthreads();
        if (tid < 64) {
            int t = (tid < 16) ? wsum[tid] : 0;
            #pragma unroll
            for (int d = 1; d < 16; d <<= 1) { int u = __shfl_up(t, d); if (tid >= d) t += u; }
            if (tid < 16) wsum[tid] = t;
        }
        __syncthreads();
        int excl = (w > 0) ? wsum[w - 1] : 0;
        int incl = s + excl + carry;
        if (i < N_NODES) rowptr[i + 1] = incl;
        __syncthreads();
        if (tid == 0) carry += wsum[15];
        __syncthreads();
    }
    for (int i = tid; i < N_NODES; i += 1024) deg[i] = 0;
}

// sE holds BYTE offsets: (src*DIM*2, e*EFEAT*2)
__global__ __launch_bounds__(256) void scatter_kernel(
    const int* __restrict__ ei, const int* __restrict__ rowptr,
    int* __restrict__ cursor, int2* __restrict__ sE)
{
    int e = blockIdx.x * 256 + threadIdx.x;
    if (e >= N_EDGES) return;
    int dst = ei[N_EDGES + e];
    int p = atomicAdd(&cursor[dst], 1);
    sE[rowptr[dst] + p] = make_int2(ei[e] * (DIM * 2), e * (EFEAT * 2));
}

// ---------------------------------------------------------------- h_in = act(src) + vn[batch]  (bf16 out)
template <bool USEBN, int VNM>
__global__ __launch_bounds__(256) void hin_kernel(
    const float* __restrict__ src,
    const float* __restrict__ sum2, const float* __restrict__ ss2,
    const float* __restrict__ g, const float* __restrict__ b, float invN,
    const int* __restrict__ batch,
    const float* __restrict__ vn_emb,
    const float* __restrict__ vnpre, const float* __restrict__ vsum, const float* __restrict__ vss,
    const float* __restrict__ gv, const float* __restrict__ btv, float invG,
    u16* __restrict__ hin, int total4)
{
    int idx = blockIdx.x * 256 + threadIdx.x;
    if (idx >= total4) return;
    int base = idx * 4;
    int n = base >> 7;
    int c = base & (DIM - 1);
    float4 v = *(const float4*)(src + base);
    float o[4] = {v.x, v.y, v.z, v.w};
    if (USEBN) {
        #pragma unroll
        for (int j = 0; j < 4; ++j) {
            int cj = c + j;
            float m = sum2[cj] * invN;
            float var = ss2[cj] * invN - m * m;
            float r = rsqrtf(var + BN_EPS);
            float a = g[cj] * r;
            o[j] = fmaxf(fmaf(a, o[j], b[cj] - m * a), 0.f);
        }
    }
    int grp = batch[n];
    if (VNM == 0) {
        const float4 w = *(const float4*)(vn_emb + c);
        o[0] += w.x; o[1] += w.y; o[2] += w.z; o[3] += w.w;
    } else {
        const float4 vp = *(const float4*)(vnpre + (size_t)grp * DIM + c);
        float vv[4] = {vp.x, vp.y, vp.z, vp.w};
        #pragma unroll
        for (int j = 0; j < 4; ++j) {
            int cj = c + j;
            float m = vsum[cj] * invG;
            float var = vss[cj] * invG - m * m;
            float r = rsqrtf(var + BN_EPS);
            float a = gv[cj] * r;
            o[j] += fmaxf(fmaf(a, vv[j], btv[cj] - m * a), 0.f);
        }
    }
    uint2 pk;
    pk.x = pk2(o[0], o[1]);
    pk.y = pk2(o[2], o[3]);
    *(uint2*)(hin + base) = pk;
}

// ---------------------------------------------------------------- gather aggregation
__device__ __forceinline__ void edge_term(
    u32 h, uint4 eq, const float2* rW, float2 rB, float2& acc)
{
    float a[8];
    float2 p;
    p = up2(eq.x); a[0] = p.x; a[1] = p.y;
    p = up2(eq.y); a[2] = p.x; a[3] = p.y;
    p = up2(eq.z); a[4] = p.x; a[5] = p.y;
    p = up2(eq.w); a[6] = p.x; a[7] = p.y;
    float ex = rB.x, ey = rB.y;
    #pragma unroll
    for (int k = 0; k < EFEAT; ++k) {
        ex = fmaf(a[k], rW[k].x, ex);
        ey = fmaf(a[k], rW[k].y, ey);
    }
    float2 hv = up2(h);
    acc.x += fmaxf(hv.x + ex, 0.f);
    acc.y += fmaxf(hv.y + ey, 0.f);
}

__global__ __launch_bounds__(256) void aggr_kernel(
    const int* __restrict__ rowptr, const int2* __restrict__ sE,
    const u16* __restrict__ eab,
    const float* __restrict__ Wel, const float* __restrict__ bel,
    const u16* __restrict__ hin, u16* __restrict__ z,
    float* __restrict__ statsZ)
{
    if (blockIdx.x == 0) {      // zero this layer's stats buffer (consumed only after aggr)
        for (int i = threadIdx.x; i < 2048; i += 256) statsZ[i] = 0.f;
    }
    int node = blockIdx.x * 4 + (threadIdx.x >> 6);
    if (node >= N_NODES) return;
    int lane = threadIdx.x & 63;
    int c = lane * 2;                 // u16 elem col
    const u32 cb = (u32)lane * 4u;    // byte col

    float2 rW[EFEAT];
    #pragma unroll
    for (int k = 0; k < EFEAT; ++k)
        rW[k] = *(const float2*)(Wel + k * DIM + c);
    const float2 rB = *(const float2*)(bel + c);

    const u32 ownb = (u32)node * (DIM * 2) + cb;
    float2 acc = up2(ld32(hin, ownb));
    int beg = rowptr[node], end = rowptr[node + 1];

    int i = beg;
    if ((i & 1) && i < end) {
        int2 s0 = sE[i];
        edge_term(ld32(hin, (u32)s0.x + cb), ld128(eab, (u32)s0.y), rW, rB, acc);
        ++i;
    }
    for (; i + 7 < end; i += 8) {
        int4 sp0 = *(const int4*)(sE + i);
        int4 sp1 = *(const int4*)(sE + i + 2);
        int4 sp2 = *(const int4*)(sE + i + 4);
        int4 sp3 = *(const int4*)(sE + i + 6);
        u32 h0 = ld32(hin, (u32)sp0.x + cb);
        u32 h1 = ld32(hin, (u32)sp0.z + cb);
        u32 h2 = ld32(hin, (u32)sp1.x + cb);
        u32 h3 = ld32(hin, (u32)sp1.z + cb);
        u32 h4 = ld32(hin, (u32)sp2.x + cb);
        u32 h5 = ld32(hin, (u32)sp2.z + cb);
        u32 h6 = ld32(hin, (u32)sp3.x + cb);
        u32 h7 = ld32(hin, (u32)sp3.z + cb);
        uint4 e0 = ld128(eab, (u32)sp0.y);
        uint4 e1 = ld128(eab, (u32)sp0.w);
        uint4 e2 = ld128(eab, (u32)sp1.y);
        uint4 e3 = ld128(eab, (u32)sp1.w);
        uint4 e4 = ld128(eab, (u32)sp2.y);
        uint4 e5 = ld128(eab, (u32)sp2.w);
        uint4 e6 = ld128(eab, (u32)sp3.y);
        uint4 e7 = ld128(eab, (u32)sp3.w);
        edge_term(h0, e0, rW, rB, acc);
        edge_term(h1, e1, rW, rB, acc);
        edge_term(h2, e2, rW, rB, acc);
        edge_term(h3, e3, rW, rB, acc);
        edge_term(h4, e4, rW, rB, acc);
        edge_term(h5, e5, rW, rB, acc);
        edge_term(h6, e6, rW, rB, acc);
        edge_term(h7, e7, rW, rB, acc);
    }
    for (; i < end; ++i) {
        int2 s0 = sE[i];
        edge_term(ld32(hin, (u32)s0.x + cb), ld128(eab, (u32)s0.y), rW, rB, acc);
    }
    *(u32*)((char*)z + ownb) = pk2(acc.x, acc.y);
}

// ---------------------------------------------------------------- bf16 MFMA GEMM, 64x64 tile, BK=128
// MODE 0: A as-is. MODE 1: A -> relu(alpha[k]*A+beta[k]) during staging. CBF16: C stored bf16 else fp32.
template <int MODE, bool CBF16>
__global__ __launch_bounds__(256) void gemm_bf16_kernel(
    const u16* __restrict__ Aa,
    const float* __restrict__ sSum, const float* __restrict__ sSS,
    const float* __restrict__ gA, const float* __restrict__ btA, float invCnt,
    const u16* __restrict__ Bt,          // [Nc][K] bf16
    const float* __restrict__ bias,
    void* __restrict__ CoutV,
    float* __restrict__ outSum, float* __restrict__ outSS,
    int M, int K, int Nc)
{
    constexpr int BM = 64, BN = 64, BK = 128;
    constexpr int LDA = BK + 8;
    __shared__ u16 As[BM * LDA];         // 17.4 KB
    __shared__ u16 Bs[BN * LDA];         // 17.4 KB
    __shared__ float csum[BN], css[BN];

    const int tid = threadIdx.x;
    const int wave = tid >> 6, lane = tid & 63;
    const int row0 = blockIdx.x * BM, col0 = blockIdx.y * BN;
    const int w_m = (wave & 1) * 32, w_n = (wave >> 1) * 32;
    const int quad = lane >> 4, l16 = lane & 15;

    if (tid < BN) { csum[tid] = 0.f; css[tid] = 0.f; }

    f32x4_t acc[2][2];
    #pragma unroll
    for (int mi = 0; mi < 2; ++mi)
        #pragma unroll
        for (int ni = 0; ni < 2; ++ni)
            acc[mi][ni] = (f32x4_t){0.f, 0.f, 0.f, 0.f};

    const int kc = (tid & 15) * 8;       // u16 elems
    const int nkt = K / BK;

    for (int kt = 0; kt < nkt; ++kt) {
        float af[8], bf_[8];
        if (MODE == 1) {
            #pragma unroll
            for (int j = 0; j < 8; ++j) {
                int kg = kt * BK + kc + j;
                float m = sSum[kg] * invCnt;
                float var = sSS[kg] * invCnt - m * m;
                float r = rsqrtf(var + BN_EPS);
                float a = gA[kg] * r;
                af[j] = a;
                bf_[j] = btA[kg] - m * a;
            }
        }
        // stage A: 64 rows x 128 k (4 iters)
        #pragma unroll
        for (int it = 0; it < 4; ++it) {
            int chunk = it * 256 + tid;
            int row = chunk >> 4;
            int gr = row0 + row; if (gr >= M) gr = M - 1;
            uint4 q = *(const uint4*)(Aa + (size_t)gr * K + kt * BK + kc);
            if (MODE == 1) {
                float2 p0 = up2(q.x), p1 = up2(q.y), p2 = up2(q.z), p3 = up2(q.w);
                p0.x = fmaxf(fmaf(af[0], p0.x, bf_[0]), 0.f);
                p0.y = fmaxf(fmaf(af[1], p0.y, bf_[1]), 0.f);
                p1.x = fmaxf(fmaf(af[2], p1.x, bf_[2]), 0.f);
                p1.y = fmaxf(fmaf(af[3], p1.y, bf_[3]), 0.f);
                p2.x = fmaxf(fmaf(af[4], p2.x, bf_[4]), 0.f);
                p2.y = fmaxf(fmaf(af[5], p2.y, bf_[5]), 0.f);
                p3.x = fmaxf(fmaf(af[6], p3.x, bf_[6]), 0.f);
                p3.y = fmaxf(fmaf(af[7], p3.y, bf_[7]), 0.f);
                q.x = pk2(p0.x, p0.y); q.y = pk2(p1.x, p1.y);
                q.z = pk2(p2.x, p2.y); q.w = pk2(p3.x, p3.y);
            }
            *(uint4*)(As + row * LDA + kc) = q;
        }
        // stage B: 64 cols x 128 k (4 iters)
        #pragma unroll
        for (int it = 0; it < 4; ++it) {
            int chunk = it * 256 + tid;
            int n = chunk >> 4;
            uint4 q = *(const uint4*)(Bt + (size_t)(col0 + n) * K + kt * BK + kc);
            *(uint4*)(Bs + n * LDA + kc) = q;
        }
        __syncthreads();
        #pragma unroll
        for (int ks = 0; ks < 4; ++ks) {
            bf16x8_t a_frag[2], b_frag[2];
            #pragma unroll
            for (int mi = 0; mi < 2; ++mi)
                a_frag[mi] = *(const bf16x8_t*)(As + (w_m + mi * 16 + l16) * LDA + ks * 32 + quad * 8);
            #pragma unroll
            for (int ni = 0; ni < 2; ++ni)
                b_frag[ni] = *(const bf16x8_t*)(Bs + (w_n + ni * 16 + l16) * LDA + ks * 32 + quad * 8);
            #pragma unroll
            for (int mi = 0; mi < 2; ++mi)
                #pragma unroll
                for (int ni = 0; ni < 2; ++ni)
                    acc[mi][ni] = __builtin_amdgcn_mfma_f32_16x16x32_bf16(
                        a_frag[mi], b_frag[ni], acc[mi][ni], 0, 0, 0);
        }
        __syncthreads();
    }

    // epilogue: C layout col=lane&15, row=quad*4+reg
    u16* Cb = (u16*)CoutV;
    float* Cf = (float*)CoutV;
    #pragma unroll
    for (int ni = 0; ni < 2; ++ni) {
        int ccol = w_n + ni * 16 + l16;
        int col = col0 + ccol;
        float bv = bias[col];
        float s = 0.f, qs = 0.f;
        #pragma unroll
        for (int mi = 0; mi < 2; ++mi) {
            int rbase = row0 + w_m + mi * 16 + quad * 4;
            #pragma unroll
            for (int reg = 0; reg < 4; ++reg) {
                int gr = rbase + reg;
                if (gr < M) {
                    float o = acc[mi][ni][reg] + bv;
                    s += o;
                    qs += o * o;
                    if (CBF16) Cb[(size_t)gr * Nc + col] = f2bf(o);
                    else       Cf[(size_t)gr * Nc + col] = o;
                }
            }
        }
        s += __shfl_xor(s, 16);  s += __shfl_xor(s, 32);
        qs += __shfl_xor(qs, 16);  qs += __shfl_xor(qs, 32);
        if (quad == 0) {
            atomicAdd(&csum[ccol], s);
            atomicAdd(&css[ccol], qs);
        }
    }
    __syncthreads();
    if (tid < BN) {
        atomic_add_f(outSum + col0 + tid, csum[tid]);
        atomic_add_f(outSS + col0 + tid, css[tid]);
    }
}

// ---------------------------------------------------------------- fp32 GEMM (VN path)
// MODE 1: A = relu(alpha*Aa+beta)           (alpha/beta from stats)
// MODE 2: A = Aa + vadd[k]                  (vn_emb broadcast)
// MODE 3: A = Aa + relu(alpha*Ab[gr,k]+beta)(vn transform of vnpre)
// ZP: zero zbuf[65536] at end (pooled re-init for next layer)
template <int MODE, bool ZP>
__global__ __launch_bounds__(256) void gemm_kernel(
    const float* __restrict__ Aa, const float* __restrict__ Ab, const float* __restrict__ vadd,
    const float* __restrict__ sSum, const float* __restrict__ sSS,
    const float* __restrict__ gA, const float* __restrict__ btA, float invCnt,
    const float* __restrict__ B, const float* __restrict__ bias,
    float* __restrict__ Cout, float* __restrict__ outSum, float* __restrict__ outSS,
    int M, int K, int Nc, float* __restrict__ zbuf)
{
    __shared__ float As[16][68];
    __shared__ float Bs[16][64];
    __shared__ float alphaS[256], betaS[256];
    __shared__ float csum[64], css[64];

    const int tid = threadIdx.x;
    const int tx = tid & 15, ty = tid >> 4;
    const int row0 = blockIdx.x * 64, col0 = blockIdx.y * 64;

    if (tid < 64) { csum[tid] = 0.f; css[tid] = 0.f; }
    if (MODE == 1 || MODE == 3) {
        for (int k = tid; k < K; k += 256) {
            float m = sSum[k] * invCnt;
            float var = sSS[k] * invCnt - m * m;
            float r = rsqrtf(var + BN_EPS);
            float a = gA[k] * r;
            alphaS[k] = a;
            betaS[k] = btA[k] - m * a;
        }
    } else if (MODE == 2) {
        for (int k = tid; k < K; k += 256) betaS[k] = vadd[k];
    }
    __syncthreads();

    float acc[4][4];
    #pragma unroll
    for (int i = 0; i < 4; ++i)
        #pragma unroll
        for (int j = 0; j < 4; ++j) acc[i][j] = 0.f;

    const int lr = tid >> 2;
    const int lk = (tid & 3) * 4;
    const int bk = tid >> 4;
    const int bc = tx * 4;

    for (int kt = 0; kt < K; kt += 16) {
        int gr = row0 + lr;
        float4 va = make_float4(0.f, 0.f, 0.f, 0.f);
        if (gr < M) {
            va = *(const float4*)(Aa + (size_t)gr * K + kt + lk);
            int k0 = kt + lk;
            if (MODE == 1) {
                va.x = fmaxf(fmaf(alphaS[k0 + 0], va.x, betaS[k0 + 0]), 0.f);
                va.y = fmaxf(fmaf(alphaS[k0 + 1], va.y, betaS[k0 + 1]), 0.f);
                va.z = fmaxf(fmaf(alphaS[k0 + 2], va.z, betaS[k0 + 2]), 0.f);
                va.w = fmaxf(fmaf(alphaS[k0 + 3], va.w, betaS[k0 + 3]), 0.f);
            } else if (MODE == 2) {
                va.x += betaS[k0 + 0]; va.y += betaS[k0 + 1];
                va.z += betaS[k0 + 2]; va.w += betaS[k0 + 3];
            } else if (MODE == 3) {
                const float4 vb = *(const float4*)(Ab + (size_t)gr * K + kt + lk);
                va.x += fmaxf(fmaf(alphaS[k0 + 0], vb.x, betaS[k0 + 0]), 0.f);
                va.y += fmaxf(fmaf(alphaS[k0 + 1], vb.y, betaS[k0 + 1]), 0.f);
                va.z += fmaxf(fmaf(alphaS[k0 + 2], vb.z, betaS[k0 + 2]), 0.f);
                va.w += fmaxf(fmaf(alphaS[k0 + 3], vb.w, betaS[k0 + 3]), 0.f);
            }
        }
        As[lk + 0][lr] = va.x;
        As[lk + 1][lr] = va.y;
        As[lk + 2][lr] = va.z;
        As[lk + 3][lr] = va.w;
        const float4 vb4 = *(const float4*)(B + (size_t)(kt + bk) * Nc + col0 + bc);
        *(float4*)&Bs[bk][bc] = vb4;
        __syncthreads();
        #pragma unroll
        for (int kk = 0; kk < 16; ++kk) {
            const float4 a4 = *(const float4*)&As[kk][ty * 4];
            const float4 b4 = *(const float4*)&Bs[kk][tx * 4];
            float av[4] = {a4.x, a4.y, a4.z, a4.w};
            float bv4[4] = {b4.x, b4.y, b4.z, b4.w};
            #pragma unroll
            for (int i = 0; i < 4; ++i)
                #pragma unroll
                for (int j = 0; j < 4; ++j)
                    acc[i][j] = fmaf(av[i], bv4[j], acc[i][j]);
        }
        __syncthreads();
    }

    const float4 bvv = *(const float4*)(bias + col0 + tx * 4);
    float bias4[4] = {bvv.x, bvv.y, bvv.z, bvv.w};
    float ps[4] = {0.f, 0.f, 0.f, 0.f};
    float pq[4] = {0.f, 0.f, 0.f, 0.f};
    #pragma unroll
    for (int i = 0; i < 4; ++i) {
        int gr = row0 + ty * 4 + i;
        if (gr < M) {
            float o[4];
            #pragma unroll
            for (int j = 0; j < 4; ++j) {
                o[j] = acc[i][j] + bias4[j];
                ps[j] += o[j];
                pq[j] += o[j] * o[j];
            }
            *(float4*)(Cout + (size_t)gr * Nc + col0 + tx * 4) = make_float4(o[0], o[1], o[2], o[3]);
        }
    }
    #pragma unroll
    for (int j = 0; j < 4; ++j) {
        atomicAdd(&csum[tx * 4 + j], ps[j]);
        atomicAdd(&css[tx * 4 + j], pq[j]);
    }
    __syncthreads();
    if (tid < 64) {
        atomic_add_f(outSum + col0 + tid, csum[tid]);
        atomic_add_f(outSS + col0 + tid, css[tid]);
    }
    if (ZP) {
        int flat = blockIdx.y * gridDim.x + blockIdx.x;
        float4* zp = (float4*)(zbuf + (size_t)flat * 4096 + tid * 16);
        zp[0] = make_float4(0.f, 0.f, 0.f, 0.f);
        zp[1] = make_float4(0.f, 0.f, 0.f, 0.f);
        zp[2] = make_float4(0.f, 0.f, 0.f, 0.f);
        zp[3] = make_float4(0.f, 0.f, 0.f, 0.f);
    }
}

// ---------------------------------------------------------------- pooled: chunked segment sum (batch sorted)
#define PCHUNK 256
__global__ __launch_bounds__(128) void pooled_chunk_kernel(
    const u16* __restrict__ hin, const int* __restrict__ batch, float* __restrict__ pooled)
{
    __shared__ int sb[PCHUNK];
    int n0 = blockIdx.x * PCHUNK;
    int cnt = N_NODES - n0; if (cnt > PCHUNK) cnt = PCHUNK;
    for (int i = threadIdx.x; i < cnt; i += 128) sb[i] = batch[n0 + i];
    __syncthreads();
    int c = threadIdx.x;
    int curg = sb[0];
    float acc = 0.f;
    for (int i = 0; i < cnt; ++i) {
        int g = sb[i];
        if (g != curg) {
            atomic_add_f(&pooled[(size_t)curg * DIM + c], acc);
            acc = 0.f;
            curg = g;
        }
        acc += bf2f(hin[(size_t)(n0 + i) * DIM + c]);
    }
    atomic_add_f(&pooled[(size_t)curg * DIM + c], acc);
}

// ---------------------------------------------------------------- final in-place BN on d_out (no relu)
__global__ __launch_bounds__(256) void final_bn_kernel(
    float* __restrict__ outp, const float* __restrict__ sum2, const float* __restrict__ ss2,
    const float* __restrict__ g, const float* __restrict__ b, float invN, int total4)
{
    int idx = blockIdx.x * 256 + threadIdx.x;
    if (idx >= total4) return;
    int base = idx * 4;
    int c = base & (DIM - 1);
    float4 v = *(const float4*)(outp + base);
    float o[4] = {v.x, v.y, v.z, v.w};
    #pragma unroll
    for (int j = 0; j < 4; ++j) {
        int cj = c + j;
        float m = sum2[cj] * invN;
        float var = ss2[cj] * invN - m * m;
        float r = rsqrtf(var + BN_EPS);
        float a = g[cj] * r;
        o[j] = fmaf(a, o[j], b[cj] - m * a);
    }
    *(float4*)(outp + base) = make_float4(o[0], o[1], o[2], o[3]);
}

// ---------------------------------------------------------------- launch
extern "C" void kernel_launch(void* const* d_in, const int* in_sizes, int n_in,
                              void* d_out, int out_size, void* d_ws, size_t ws_size,
                              hipStream_t stream) {
    const float* x         = (const float*)d_in[0];
    const float* edge_attr = (const float*)d_in[1];
    const float* vn_emb    = (const float*)d_in[2];
    const float* We        = (const float*)d_in[3];
    const float* be        = (const float*)d_in[4];
    const float* W1        = (const float*)d_in[5];
    const float* b1        = (const float*)d_in[6];
    const float* g1v       = (const float*)d_in[7];
    const float* bt1       = (const float*)d_in[8];
    const float* W2        = (const float*)d_in[9];
    const float* b2        = (const float*)d_in[10];
    const float* gb        = (const float*)d_in[11];
    const float* bb        = (const float*)d_in[12];
    const float* Wv1       = (const float*)d_in[13];
    const float* bv1       = (const float*)d_in[14];
    const float* gv1       = (const float*)d_in[15];
    const float* btv1      = (const float*)d_in[16];
    const float* Wv2       = (const float*)d_in[17];
    const float* bv2       = (const float*)d_in[18];
    const float* gv2       = (const float*)d_in[19];
    const float* btv2      = (const float*)d_in[20];
    const int* edge_index  = (const int*)d_in[21];
    const int* batch       = (const int*)d_in[22];
    float* outp = (float*)d_out;

    auto au = [](size_t v) { return (v + 255) & ~(size_t)255; };
    char* p = (char*)d_ws;
    u16* h_in   = (u16*)p;  p += au((size_t)N_NODES * DIM * 2);
    u16* z_bf   = (u16*)p;  p += au((size_t)N_NODES * DIM * 2);
    u16* c1_bf  = (u16*)p;  p += au((size_t)N_NODES * HID * 2);
    u16* eab    = (u16*)p;  p += au((size_t)N_EDGES * EFEAT * 2);
    u16* W1t    = (u16*)p;  p += au((size_t)3 * 32768 * 2);
    u16* W2t    = (u16*)p;  p += au((size_t)3 * 32768 * 2);
    float* pooled = (float*)p;  p += au((size_t)N_GRAPH * DIM * 4);
    float* tpre   = (float*)p;  p += au((size_t)N_GRAPH * HID * 4);
    float* vnpre  = (float*)p;  p += au((size_t)N_GRAPH * DIM * 4);
    float* statsA = (float*)p;  p += au(2048 * 4);
    float* statsB = (float*)p;  p += au(2048 * 4);
    int* rowptr = (int*)p;  p += au((size_t)(N_NODES + 1) * 4);
    int* cursor = (int*)p;  p += au((size_t)N_NODES * 4);
    int2* sE    = (int2*)p;

    const float invN = 1.0f / (float)N_NODES;
    const float invG = 1.0f / (float)N_GRAPH;
    const int total4 = N_NODES * DIM / 4;

    // ---- one-time prep ----
    hipMemsetAsync(cursor, 0, N_NODES * sizeof(int), stream);
    hipMemsetAsync(pooled, 0, (size_t)N_GRAPH * DIM * sizeof(float), stream);
    hist_kernel<<<(N_EDGES + 255) / 256, 256, 0, stream>>>(edge_index, cursor);
    scan_kernel<<<1, 1024, 0, stream>>>(cursor, rowptr);   // also re-zeroes cursor
    scatter_kernel<<<(N_EDGES + 255) / 256, 256, 0, stream>>>(edge_index, rowptr, cursor, sE);
    wconv_kernel<<<768, 256, 0, stream>>>(W1, W2, W1t, W2t);
    eaconv_kernel<<<(N_EDGES + 255) / 256, 256, 0, stream>>>(edge_attr, eab);

    for (int l = 0; l < N_LAYER; ++l) {
        float* cur = (l & 1) ? statsB : statsA;
        float* prv = (l & 1) ? statsA : statsB;

        if (l == 0)
            hin_kernel<false, 0><<<(total4 + 255) / 256, 256, 0, stream>>>(
                x, nullptr, nullptr, nullptr, nullptr, 0.f, batch,
                vn_emb, nullptr, nullptr, nullptr, nullptr, nullptr, 0.f,
                h_in, total4);
        else
            hin_kernel<true, 1><<<(total4 + 255) / 256, 256, 0, stream>>>(
                outp, prv + 512, prv + 640, gb + (size_t)(l - 1) * DIM, bb + (size_t)(l - 1) * DIM,
                invN, batch,
                nullptr, vnpre, prv + 1280, prv + 1408,
                gv2 + (size_t)(l - 1) * DIM, btv2 + (size_t)(l - 1) * DIM, invG,
                h_in, total4);

        if (l < N_LAYER - 1)
            pooled_chunk_kernel<<<(N_NODES + PCHUNK - 1) / PCHUNK, 128, 0, stream>>>(
                h_in, batch, pooled);

        aggr_kernel<<<(N_NODES + 3) / 4, 256, 0, stream>>>(
            rowptr, sE, eab, We + (size_t)l * EFEAT * DIM, be + (size_t)l * DIM,
            h_in, z_bf, cur);

        dim3 g1d((N_NODES + 63) / 64, HID / 64);
        gemm_bf16_kernel<0, true><<<g1d, 256, 0, stream>>>(
            z_bf, nullptr, nullptr, nullptr, nullptr, 0.f,
            W1t + (size_t)l * 32768, b1 + (size_t)l * HID,
            (void*)c1_bf, cur + 0, cur + 256, N_NODES, DIM, HID);

        dim3 g2d((N_NODES + 63) / 64, DIM / 64);
        gemm_bf16_kernel<1, false><<<g2d, 256, 0, stream>>>(
            c1_bf, cur + 0, cur + 256, g1v + (size_t)l * HID, bt1 + (size_t)l * HID, invN,
            W2t + (size_t)l * 32768, b2 + (size_t)l * DIM,
            (void*)outp, cur + 512, cur + 640, N_NODES, HID, DIM);

        if (l < N_LAYER - 1) {
            dim3 g3d(N_GRAPH / 64, HID / 64);
            if (l == 0)
                gemm_kernel<2, false><<<g3d, 256, 0, stream>>>(
                    pooled, nullptr, vn_emb,
                    nullptr, nullptr, nullptr, nullptr, 0.f,
                    Wv1 + (size_t)l * DIM * HID, bv1 + (size_t)l * HID,
                    tpre, cur + 768, cur + 1024, N_GRAPH, DIM, HID, nullptr);
            else
                gemm_kernel<3, false><<<g3d, 256, 0, stream>>>(
                    pooled, vnpre, nullptr,
                    prv + 1280, prv + 1408, gv2 + (size_t)(l - 1) * DIM, btv2 + (size_t)(l - 1) * DIM, invG,
                    Wv1 + (size_t)l * DIM * HID, bv1 + (size_t)l * HID,
                    tpre, cur + 768, cur + 1024, N_GRAPH, DIM, HID, nullptr);

            dim3 g4d(N_GRAPH / 64, DIM / 64);
            gemm_kernel<1, true><<<g4d, 256, 0, stream>>>(
                tpre, nullptr, nullptr,
                cur + 768, cur + 1024, gv1 + (size_t)l * HID, btv1 + (size_t)l * HID, invG,
                Wv2 + (size_t)l * HID * DIM, bv2 + (size_t)l * DIM,
                vnpre, cur + 1280, cur + 1408, N_GRAPH, HID, DIM, pooled);
        }
    }

    float* lastStats = statsA;   // layer 2 parity 0
    final_bn_kernel<<<(total4 + 255) / 256, 256, 0, stream>>>(
        outp, lastStats + 512, lastStats + 640, gb + (size_t)2 * DIM, bb + (size_t)2 * DIM, invN, total4);
}

// Round 6
// 987.881 us; speedup vs baseline: 1.1039x; 1.1039x over previous
//
#include <hip/hip_runtime.h>
#include <hip/hip_bf16.h>

#define N_NODES 50000
#define N_EDGES 800000
#define DIM 128
#define HID 256
#define N_GRAPH 512
#define N_LAYER 3
#define EFEAT 8
#define BN_EPS 1e-5f

typedef unsigned short u16;
typedef unsigned int u32;

using bf16x8_t = short __attribute__((ext_vector_type(8)));
using f32x4_t  = float __attribute__((ext_vector_type(4)));
using f32x2    = float __attribute__((ext_vector_type(2)));

// ---------------------------------------------------------------- utilities
__device__ __forceinline__ void atomic_add_f(float* p, float v) { unsafeAtomicAdd(p, v); }
__device__ __forceinline__ u16 f2bf(float x) {
    union { float f; u32 u; } v; v.f = x;
    u32 r = v.u + 0x7FFF + ((v.u >> 16) & 1);
    return (u16)(r >> 16);
}
__device__ __forceinline__ float bf2f(u16 u) {
    union { u32 i; float f; } v; v.i = (u32)u << 16; return v.f;
}
__device__ __forceinline__ float2 up2(u32 p) {
    return make_float2(bf2f((u16)(p & 0xFFFF)), bf2f((u16)(p >> 16)));
}
__device__ __forceinline__ u32 pk2(float a, float b) {
    return (u32)f2bf(a) | ((u32)f2bf(b) << 16);
}
__device__ __forceinline__ u32 ld32(const u16* base, u32 boff) {
    return *(const u32*)((const char*)base + boff);
}

// ---------------------------------------------------------------- weight transpose+convert to bf16
__global__ __launch_bounds__(256) void wconv_kernel(
    const float* __restrict__ W1, const float* __restrict__ W2,
    u16* __restrict__ W1t, u16* __restrict__ W2t)
{
    int idx = blockIdx.x * 256 + threadIdx.x;
    if (idx >= 6 * 32768) return;
    int m = idx >> 15;
    int off = idx & 32767;
    int l = m >> 1;
    if ((m & 1) == 0) {
        int r = off >> 8, c = off & 255;
        W1t[(size_t)l * 32768 + c * 128 + r] = f2bf(W1[(size_t)l * 32768 + r * 256 + c]);
    } else {
        int r = off >> 7, c = off & 127;
        W2t[(size_t)l * 32768 + c * 256 + r] = f2bf(W2[(size_t)l * 32768 + r * 128 + c]);
    }
}

// ---------------------------------------------------------------- CSR build
__global__ __launch_bounds__(256) void hist_kernel(const int* __restrict__ ei, int* __restrict__ deg) {
    int e = blockIdx.x * 256 + threadIdx.x;
    if (e < N_EDGES) atomicAdd(&deg[ei[N_EDGES + e]], 1);
}

// exclusive scan deg -> rowptr, then zero deg (reused as cursor by scatter)
__global__ __launch_bounds__(1024) void scan_kernel(int* __restrict__ deg, int* __restrict__ rowptr) {
    __shared__ int wsum[16];
    __shared__ int carry;
    int tid = threadIdx.x;
    if (tid == 0) { carry = 0; rowptr[0] = 0; }
    __syncthreads();
    for (int base = 0; base < N_NODES; base += 1024) {
        int i = base + tid;
        int v = (i < N_NODES) ? deg[i] : 0;
        int lane = tid & 63, w = tid >> 6;
        int s = v;
        #pragma unroll
        for (int d = 1; d < 64; d <<= 1) { int t = __shfl_up(s, d); if (lane >= d) s += t; }
        if (lane == 63) wsum[w] = s;
        __syncthreads();
        if (tid < 64) {
            int t = (tid < 16) ? wsum[tid] : 0;
            #pragma unroll
            for (int d = 1; d < 16; d <<= 1) { int u = __shfl_up(t, d); if (tid >= d) t += u; }
            if (tid < 16) wsum[tid] = t;
        }
        __syncthreads();
        int excl = (w > 0) ? wsum[w - 1] : 0;
        int incl = s + excl + carry;
        if (i < N_NODES) rowptr[i + 1] = incl;
        __syncthreads();
        if (tid == 0) carry += wsum[15];
        __syncthreads();
    }
    for (int i = tid; i < N_NODES; i += 1024) deg[i] = 0;
}

// sE holds BYTE offsets: (src*DIM*2, e*EFEAT*4)
__global__ __launch_bounds__(256) void scatter_kernel(
    const int* __restrict__ ei, const int* __restrict__ rowptr,
    int* __restrict__ cursor, int2* __restrict__ sE)
{
    int e = blockIdx.x * 256 + threadIdx.x;
    if (e >= N_EDGES) return;
    int dst = ei[N_EDGES + e];
    int p = atomicAdd(&cursor[dst], 1);
    sE[rowptr[dst] + p] = make_int2(ei[e] * (DIM * 2), e * (EFEAT * 4));
}

// ---------------------------------------------------------------- h_in = act(src) + vn[batch]  (bf16 out)
template <bool USEBN, int VNM>
__global__ __launch_bounds__(256) void hin_kernel(
    const float* __restrict__ src,
    const float* __restrict__ sum2, const float* __restrict__ ss2,
    const float* __restrict__ g, const float* __restrict__ b, float invN,
    const int* __restrict__ batch,
    const float* __restrict__ vn_emb,
    const float* __restrict__ vnpre, const float* __restrict__ vsum, const float* __restrict__ vss,
    const float* __restrict__ gv, const float* __restrict__ btv, float invG,
    u16* __restrict__ hin, int total4)
{
    int idx = blockIdx.x * 256 + threadIdx.x;
    if (idx >= total4) return;
    int base = idx * 4;
    int n = base >> 7;
    int c = base & (DIM - 1);
    float4 v = *(const float4*)(src + base);
    float o[4] = {v.x, v.y, v.z, v.w};
    if (USEBN) {
        #pragma unroll
        for (int j = 0; j < 4; ++j) {
            int cj = c + j;
            float m = sum2[cj] * invN;
            float var = ss2[cj] * invN - m * m;
            float r = rsqrtf(var + BN_EPS);
            float a = g[cj] * r;
            o[j] = fmaxf(fmaf(a, o[j], b[cj] - m * a), 0.f);
        }
    }
    int grp = batch[n];
    if (VNM == 0) {
        const float4 w = *(const float4*)(vn_emb + c);
        o[0] += w.x; o[1] += w.y; o[2] += w.z; o[3] += w.w;
    } else {
        const float4 vp = *(const float4*)(vnpre + (size_t)grp * DIM + c);
        float vv[4] = {vp.x, vp.y, vp.z, vp.w};
        #pragma unroll
        for (int j = 0; j < 4; ++j) {
            int cj = c + j;
            float m = vsum[cj] * invG;
            float var = vss[cj] * invG - m * m;
            float r = rsqrtf(var + BN_EPS);
            float a = gv[cj] * r;
            o[j] += fmaxf(fmaf(a, vv[j], btv[cj] - m * a), 0.f);
        }
    }
    uint2 pk;
    pk.x = pk2(o[0], o[1]);
    pk.y = pk2(o[2], o[3]);
    *(uint2*)(hin + base) = pk;
}

// ---------------------------------------------------------------- gather aggregation (f32x2 packed math)
__device__ __forceinline__ void edge_term_f(
    u32 h, float4 alo, float4 ahi, const f32x2* rW, f32x2 rB, f32x2& acc)
{
    f32x2 e = rB;
    e += alo.x * rW[0]; e += alo.y * rW[1];
    e += alo.z * rW[2]; e += alo.w * rW[3];
    e += ahi.x * rW[4]; e += ahi.y * rW[5];
    e += ahi.z * rW[6]; e += ahi.w * rW[7];
    f32x2 hv;
    hv.x = bf2f((u16)(h & 0xFFFF));
    hv.y = bf2f((u16)(h >> 16));
    f32x2 m = hv + e;
    m.x = fmaxf(m.x, 0.f);
    m.y = fmaxf(m.y, 0.f);
    acc += m;
}

__global__ __launch_bounds__(256) void aggr_kernel(
    const int* __restrict__ rowptr, const int2* __restrict__ sE,
    const float* __restrict__ ea,
    const float* __restrict__ Wel, const float* __restrict__ bel,
    const u16* __restrict__ hin, u16* __restrict__ z,
    float* __restrict__ statsZ)
{
    if (blockIdx.x == 0) {      // zero this layer's stats buffer (consumed only after aggr)
        for (int i = threadIdx.x; i < 2048; i += 256) statsZ[i] = 0.f;
    }
    int node = blockIdx.x * 4 + (threadIdx.x >> 6);
    if (node >= N_NODES) return;
    int lane = threadIdx.x & 63;
    int c = lane * 2;
    const u32 cb = (u32)lane * 4u;

    f32x2 rW[EFEAT];
    #pragma unroll
    for (int k = 0; k < EFEAT; ++k) {
        float2 t = *(const float2*)(Wel + k * DIM + c);
        rW[k].x = t.x; rW[k].y = t.y;
    }
    f32x2 rB;
    { float2 t = *(const float2*)(bel + c); rB.x = t.x; rB.y = t.y; }

    const u32 ownb = (u32)node * (DIM * 2) + cb;
    float2 own = up2(ld32(hin, ownb));
    f32x2 acc; acc.x = own.x; acc.y = own.y;
    int beg = rowptr[node], end = rowptr[node + 1];

    const char* eab = (const char*)ea;
    int i = beg;
    if ((i & 1) && i < end) {
        int2 s0 = sE[i];
        u32 h0 = ld32(hin, (u32)s0.x + cb);
        float4 a0l = *(const float4*)(eab + (u32)s0.y);
        float4 a0h = *(const float4*)(eab + (u32)s0.y + 16);
        edge_term_f(h0, a0l, a0h, rW, rB, acc);
        ++i;
    }
    for (; i + 3 < end; i += 4) {
        int4 sp0 = *(const int4*)(sE + i);
        int4 sp1 = *(const int4*)(sE + i + 2);
        u32 h0 = ld32(hin, (u32)sp0.x + cb);
        u32 h1 = ld32(hin, (u32)sp0.z + cb);
        u32 h2 = ld32(hin, (u32)sp1.x + cb);
        u32 h3 = ld32(hin, (u32)sp1.z + cb);
        float4 a0l = *(const float4*)(eab + (u32)sp0.y);
        float4 a0h = *(const float4*)(eab + (u32)sp0.y + 16);
        float4 a1l = *(const float4*)(eab + (u32)sp0.w);
        float4 a1h = *(const float4*)(eab + (u32)sp0.w + 16);
        float4 a2l = *(const float4*)(eab + (u32)sp1.y);
        float4 a2h = *(const float4*)(eab + (u32)sp1.y + 16);
        float4 a3l = *(const float4*)(eab + (u32)sp1.w);
        float4 a3h = *(const float4*)(eab + (u32)sp1.w + 16);
        edge_term_f(h0, a0l, a0h, rW, rB, acc);
        edge_term_f(h1, a1l, a1h, rW, rB, acc);
        edge_term_f(h2, a2l, a2h, rW, rB, acc);
        edge_term_f(h3, a3l, a3h, rW, rB, acc);
    }
    for (; i < end; ++i) {
        int2 s0 = sE[i];
        u32 h0 = ld32(hin, (u32)s0.x + cb);
        float4 a0l = *(const float4*)(eab + (u32)s0.y);
        float4 a0h = *(const float4*)(eab + (u32)s0.y + 16);
        edge_term_f(h0, a0l, a0h, rW, rB, acc);
    }
    *(u32*)((char*)z + ownb) = pk2(acc.x, acc.y);
}

// ---------------------------------------------------------------- bf16 MFMA GEMM, 128x128 tile (two B-halves), BK=128
// XOR-swizzled LDS (LDA=128, no pad): 16B chunk c of row r stored at c^(r&15).
// Fragment rows satisfy row&15==l16, so reads use chunk=(ks*4+quad)^l16 -> conflict-free.
// MODE 0: A as-is. MODE 1: A -> relu(alpha[k]*A+beta[k]) during staging. CBF16: C stored bf16 else fp32.
template <int MODE, bool CBF16>
__global__ __launch_bounds__(256) void gemm_bf16_kernel(
    const u16* __restrict__ Aa,
    const float* __restrict__ sSum, const float* __restrict__ sSS,
    const float* __restrict__ gA, const float* __restrict__ btA, float invCnt,
    const u16* __restrict__ Bt,          // [Nc][K] bf16
    const float* __restrict__ bias,
    void* __restrict__ CoutV,
    float* __restrict__ outSum, float* __restrict__ outSS,
    int M, int K, int Nc)
{
    constexpr int BM = 128, BN = 128, BK = 128;
    __shared__ u16 As[BM * BK];          // 32 KB
    __shared__ u16 Bs[64 * BK];          // 16 KB
    __shared__ float csum[BN], css[BN];

    const int tid = threadIdx.x;
    const int wave = tid >> 6, lane = tid & 63;
    const int row0 = blockIdx.x * BM, col0 = blockIdx.y * BN;
    const int w_m = (wave & 1) * 64, w_n = (wave >> 1) * 32;
    const int quad = lane >> 4, l16 = lane & 15;

    if (tid < BN) { csum[tid] = 0.f; css[tid] = 0.f; }

    f32x4_t acc[4][4];                   // [mi][half*2+ni]
    #pragma unroll
    for (int mi = 0; mi < 4; ++mi)
        #pragma unroll
        for (int ni = 0; ni < 4; ++ni)
            acc[mi][ni] = (f32x4_t){0.f, 0.f, 0.f, 0.f};

    const int cj = tid & 15;             // 16B chunk index within row
    const int kc = cj * 8;               // u16 offset within row (global)
    const int nkt = K / BK;

    for (int kt = 0; kt < nkt; ++kt) {
        float af[8], bf_[8];
        if (MODE == 1) {
            #pragma unroll
            for (int j = 0; j < 8; ++j) {
                int kg = kt * BK + kc + j;
                float m = sSum[kg] * invCnt;
                float var = sSS[kg] * invCnt - m * m;
                float r = rsqrtf(var + BN_EPS);
                float a = gA[kg] * r;
                af[j] = a;
                bf_[j] = btA[kg] - m * a;
            }
        }
        // stage A: 128 rows x 128 k, swizzled
        #pragma unroll
        for (int it = 0; it < 8; ++it) {
            int chunk = it * 256 + tid;
            int row = chunk >> 4;
            int gr = row0 + row; if (gr >= M) gr = M - 1;
            uint4 q = *(const uint4*)(Aa + (size_t)gr * K + kt * BK + kc);
            if (MODE == 1) {
                float2 p0 = up2(q.x), p1 = up2(q.y), p2 = up2(q.z), p3 = up2(q.w);
                p0.x = fmaxf(fmaf(af[0], p0.x, bf_[0]), 0.f);
                p0.y = fmaxf(fmaf(af[1], p0.y, bf_[1]), 0.f);
                p1.x = fmaxf(fmaf(af[2], p1.x, bf_[2]), 0.f);
                p1.y = fmaxf(fmaf(af[3], p1.y, bf_[3]), 0.f);
                p2.x = fmaxf(fmaf(af[4], p2.x, bf_[4]), 0.f);
                p2.y = fmaxf(fmaf(af[5], p2.y, bf_[5]), 0.f);
                p3.x = fmaxf(fmaf(af[6], p3.x, bf_[6]), 0.f);
                p3.y = fmaxf(fmaf(af[7], p3.y, bf_[7]), 0.f);
                q.x = pk2(p0.x, p0.y); q.y = pk2(p1.x, p1.y);
                q.z = pk2(p2.x, p2.y); q.w = pk2(p3.x, p3.y);
            }
            *(uint4*)(As + row * BK + (cj ^ (row & 15)) * 8) = q;
        }
        #pragma unroll
        for (int half = 0; half < 2; ++half) {
            // stage B half: 64 cols x 128 k, swizzled
            #pragma unroll
            for (int it = 0; it < 4; ++it) {
                int chunk = it * 256 + tid;
                int n = chunk >> 4;
                uint4 q = *(const uint4*)(Bt + (size_t)(col0 + half * 64 + n) * K + kt * BK + kc);
                *(uint4*)(Bs + n * BK + (cj ^ (n & 15)) * 8) = q;
            }
            __syncthreads();
            #pragma unroll
            for (int ks = 0; ks < 4; ++ks) {
                const int fc = ((ks * 4 + quad) ^ l16) * 8;
                bf16x8_t a_frag[4], b_frag[2];
                #pragma unroll
                for (int mi = 0; mi < 4; ++mi)
                    a_frag[mi] = *(const bf16x8_t*)(As + (w_m + mi * 16 + l16) * BK + fc);
                #pragma unroll
                for (int ni = 0; ni < 2; ++ni)
                    b_frag[ni] = *(const bf16x8_t*)(Bs + (w_n + ni * 16 + l16) * BK + fc);
                #pragma unroll
                for (int mi = 0; mi < 4; ++mi)
                    #pragma unroll
                    for (int ni = 0; ni < 2; ++ni)
                        acc[mi][half * 2 + ni] = __builtin_amdgcn_mfma_f32_16x16x32_bf16(
                            a_frag[mi], b_frag[ni], acc[mi][half * 2 + ni], 0, 0, 0);
            }
            __syncthreads();
        }
    }

    // epilogue: C layout col=lane&15, row=quad*4+reg
    u16* Cb = (u16*)CoutV;
    float* Cf = (float*)CoutV;
    #pragma unroll
    for (int half = 0; half < 2; ++half)
    #pragma unroll
    for (int ni = 0; ni < 2; ++ni) {
        int ccol = half * 64 + w_n + ni * 16 + l16;
        int col = col0 + ccol;
        float bv = bias[col];
        float s = 0.f, qs = 0.f;
        #pragma unroll
        for (int mi = 0; mi < 4; ++mi) {
            int rbase = row0 + w_m + mi * 16 + quad * 4;
            #pragma unroll
            for (int reg = 0; reg < 4; ++reg) {
                int gr = rbase + reg;
                if (gr < M) {
                    float o = acc[mi][half * 2 + ni][reg] + bv;
                    s += o;
                    qs += o * o;
                    if (CBF16) Cb[(size_t)gr * Nc + col] = f2bf(o);
                    else       Cf[(size_t)gr * Nc + col] = o;
                }
            }
        }
        s += __shfl_xor(s, 16);  s += __shfl_xor(s, 32);
        qs += __shfl_xor(qs, 16);  qs += __shfl_xor(qs, 32);
        if (quad == 0) {
            atomicAdd(&csum[ccol], s);
            atomicAdd(&css[ccol], qs);
        }
    }
    __syncthreads();
    if (tid < BN) {
        atomic_add_f(outSum + col0 + tid, csum[tid]);
        atomic_add_f(outSS + col0 + tid, css[tid]);
    }
}

// ---------------------------------------------------------------- fp32 GEMM (VN path)
// MODE 1: A = relu(alpha*Aa+beta)
// MODE 2: A = Aa + vadd[k]
// MODE 3: A = Aa + relu(alpha*Ab[gr,k]+beta)
// ZP: zero zbuf (pooled re-init for next layer)
template <int MODE, bool ZP>
__global__ __launch_bounds__(256) void gemm_kernel(
    const float* __restrict__ Aa, const float* __restrict__ Ab, const float* __restrict__ vadd,
    const float* __restrict__ sSum, const float* __restrict__ sSS,
    const float* __restrict__ gA, const float* __restrict__ btA, float invCnt,
    const float* __restrict__ B, const float* __restrict__ bias,
    float* __restrict__ Cout, float* __restrict__ outSum, float* __restrict__ outSS,
    int M, int K, int Nc, float* __restrict__ zbuf)
{
    __shared__ float As[16][68];
    __shared__ float Bs[16][64];
    __shared__ float alphaS[256], betaS[256];
    __shared__ float csum[64], css[64];

    const int tid = threadIdx.x;
    const int tx = tid & 15, ty = tid >> 4;
    const int row0 = blockIdx.x * 64, col0 = blockIdx.y * 64;

    if (tid < 64) { csum[tid] = 0.f; css[tid] = 0.f; }
    if (MODE == 1 || MODE == 3) {
        for (int k = tid; k < K; k += 256) {
            float m = sSum[k] * invCnt;
            float var = sSS[k] * invCnt - m * m;
            float r = rsqrtf(var + BN_EPS);
            float a = gA[k] * r;
            alphaS[k] = a;
            betaS[k] = btA[k] - m * a;
        }
    } else if (MODE == 2) {
        for (int k = tid; k < K; k += 256) betaS[k] = vadd[k];
    }
    __syncthreads();

    float acc[4][4];
    #pragma unroll
    for (int i = 0; i < 4; ++i)
        #pragma unroll
        for (int j = 0; j < 4; ++j) acc[i][j] = 0.f;

    const int lr = tid >> 2;
    const int lk = (tid & 3) * 4;
    const int bk = tid >> 4;
    const int bc = tx * 4;

    for (int kt = 0; kt < K; kt += 16) {
        int gr = row0 + lr;
        float4 va = make_float4(0.f, 0.f, 0.f, 0.f);
        if (gr < M) {
            va = *(const float4*)(Aa + (size_t)gr * K + kt + lk);
            int k0 = kt + lk;
            if (MODE == 1) {
                va.x = fmaxf(fmaf(alphaS[k0 + 0], va.x, betaS[k0 + 0]), 0.f);
                va.y = fmaxf(fmaf(alphaS[k0 + 1], va.y, betaS[k0 + 1]), 0.f);
                va.z = fmaxf(fmaf(alphaS[k0 + 2], va.z, betaS[k0 + 2]), 0.f);
                va.w = fmaxf(fmaf(alphaS[k0 + 3], va.w, betaS[k0 + 3]), 0.f);
            } else if (MODE == 2) {
                va.x += betaS[k0 + 0]; va.y += betaS[k0 + 1];
                va.z += betaS[k0 + 2]; va.w += betaS[k0 + 3];
            } else if (MODE == 3) {
                const float4 vb = *(const float4*)(Ab + (size_t)gr * K + kt + lk);
                va.x += fmaxf(fmaf(alphaS[k0 + 0], vb.x, betaS[k0 + 0]), 0.f);
                va.y += fmaxf(fmaf(alphaS[k0 + 1], vb.y, betaS[k0 + 1]), 0.f);
                va.z += fmaxf(fmaf(alphaS[k0 + 2], vb.z, betaS[k0 + 2]), 0.f);
                va.w += fmaxf(fmaf(alphaS[k0 + 3], vb.w, betaS[k0 + 3]), 0.f);
            }
        }
        As[lk + 0][lr] = va.x;
        As[lk + 1][lr] = va.y;
        As[lk + 2][lr] = va.z;
        As[lk + 3][lr] = va.w;
        const float4 vb4 = *(const float4*)(B + (size_t)(kt + bk) * Nc + col0 + bc);
        *(float4*)&Bs[bk][bc] = vb4;
        __syncthreads();
        #pragma unroll
        for (int kk = 0; kk < 16; ++kk) {
            const float4 a4 = *(const float4*)&As[kk][ty * 4];
            const float4 b4 = *(const float4*)&Bs[kk][tx * 4];
            float av[4] = {a4.x, a4.y, a4.z, a4.w};
            float bv4[4] = {b4.x, b4.y, b4.z, b4.w};
            #pragma unroll
            for (int i = 0; i < 4; ++i)
                #pragma unroll
                for (int j = 0; j < 4; ++j)
                    acc[i][j] = fmaf(av[i], bv4[j], acc[i][j]);
        }
        __syncthreads();
    }

    const float4 bvv = *(const float4*)(bias + col0 + tx * 4);
    float bias4[4] = {bvv.x, bvv.y, bvv.z, bvv.w};
    float ps[4] = {0.f, 0.f, 0.f, 0.f};
    float pq[4] = {0.f, 0.f, 0.f, 0.f};
    #pragma unroll
    for (int i = 0; i < 4; ++i) {
        int gr = row0 + ty * 4 + i;
        if (gr < M) {
            float o[4];
            #pragma unroll
            for (int j = 0; j < 4; ++j) {
                o[j] = acc[i][j] + bias4[j];
                ps[j] += o[j];
                pq[j] += o[j] * o[j];
            }
            *(float4*)(Cout + (size_t)gr * Nc + col0 + tx * 4) = make_float4(o[0], o[1], o[2], o[3]);
        }
    }
    #pragma unroll
    for (int j = 0; j < 4; ++j) {
        atomicAdd(&csum[tx * 4 + j], ps[j]);
        atomicAdd(&css[tx * 4 + j], pq[j]);
    }
    __syncthreads();
    if (tid < 64) {
        atomic_add_f(outSum + col0 + tid, csum[tid]);
        atomic_add_f(outSS + col0 + tid, css[tid]);
    }
    if (ZP) {
        int flat = blockIdx.y * gridDim.x + blockIdx.x;
        float4* zp = (float4*)(zbuf + (size_t)flat * 4096 + tid * 16);
        zp[0] = make_float4(0.f, 0.f, 0.f, 0.f);
        zp[1] = make_float4(0.f, 0.f, 0.f, 0.f);
        zp[2] = make_float4(0.f, 0.f, 0.f, 0.f);
        zp[3] = make_float4(0.f, 0.f, 0.f, 0.f);
    }
}

// ---------------------------------------------------------------- pooled: chunked segment sum (batch sorted)
#define PCHUNK 256
__global__ __launch_bounds__(128) void pooled_chunk_kernel(
    const u16* __restrict__ hin, const int* __restrict__ batch, float* __restrict__ pooled)
{
    __shared__ int sb[PCHUNK];
    int n0 = blockIdx.x * PCHUNK;
    int cnt = N_NODES - n0; if (cnt > PCHUNK) cnt = PCHUNK;
    for (int i = threadIdx.x; i < cnt; i += 128) sb[i] = batch[n0 + i];
    __syncthreads();
    int c = threadIdx.x;
    int curg = sb[0];
    float acc = 0.f;
    for (int i = 0; i < cnt; ++i) {
        int g = sb[i];
        if (g != curg) {
            atomic_add_f(&pooled[(size_t)curg * DIM + c], acc);
            acc = 0.f;
            curg = g;
        }
        acc += bf2f(hin[(size_t)(n0 + i) * DIM + c]);
    }
    atomic_add_f(&pooled[(size_t)curg * DIM + c], acc);
}

// ---------------------------------------------------------------- final in-place BN on d_out (no relu)
__global__ __launch_bounds__(256) void final_bn_kernel(
    float* __restrict__ outp, const float* __restrict__ sum2, const float* __restrict__ ss2,
    const float* __restrict__ g, const float* __restrict__ b, float invN, int total4)
{
    int idx = blockIdx.x * 256 + threadIdx.x;
    if (idx >= total4) return;
    int base = idx * 4;
    int c = base & (DIM - 1);
    float4 v = *(const float4*)(outp + base);
    float o[4] = {v.x, v.y, v.z, v.w};
    #pragma unroll
    for (int j = 0; j < 4; ++j) {
        int cj = c + j;
        float m = sum2[cj] * invN;
        float var = ss2[cj] * invN - m * m;
        float r = rsqrtf(var + BN_EPS);
        float a = g[cj] * r;
        o[j] = fmaf(a, o[j], b[cj] - m * a);
    }
    *(float4*)(outp + base) = make_float4(o[0], o[1], o[2], o[3]);
}

// ---------------------------------------------------------------- launch
extern "C" void kernel_launch(void* const* d_in, const int* in_sizes, int n_in,
                              void* d_out, int out_size, void* d_ws, size_t ws_size,
                              hipStream_t stream) {
    const float* x         = (const float*)d_in[0];
    const float* edge_attr = (const float*)d_in[1];
    const float* vn_emb    = (const float*)d_in[2];
    const float* We        = (const float*)d_in[3];
    const float* be        = (const float*)d_in[4];
    const float* W1        = (const float*)d_in[5];
    const float* b1        = (const float*)d_in[6];
    const float* g1v       = (const float*)d_in[7];
    const float* bt1       = (const float*)d_in[8];
    const float* W2        = (const float*)d_in[9];
    const float* b2        = (const float*)d_in[10];
    const float* gb        = (const float*)d_in[11];
    const float* bb        = (const float*)d_in[12];
    const float* Wv1       = (const float*)d_in[13];
    const float* bv1       = (const float*)d_in[14];
    const float* gv1       = (const float*)d_in[15];
    const float* btv1      = (const float*)d_in[16];
    const float* Wv2       = (const float*)d_in[17];
    const float* bv2       = (const float*)d_in[18];
    const float* gv2       = (const float*)d_in[19];
    const float* btv2      = (const float*)d_in[20];
    const int* edge_index  = (const int*)d_in[21];
    const int* batch       = (const int*)d_in[22];
    float* outp = (float*)d_out;

    auto au = [](size_t v) { return (v + 255) & ~(size_t)255; };
    char* p = (char*)d_ws;
    u16* h_in   = (u16*)p;  p += au((size_t)N_NODES * DIM * 2);
    u16* z_bf   = (u16*)p;  p += au((size_t)N_NODES * DIM * 2);
    u16* c1_bf  = (u16*)p;  p += au((size_t)N_NODES * HID * 2);
    u16* W1t    = (u16*)p;  p += au((size_t)3 * 32768 * 2);
    u16* W2t    = (u16*)p;  p += au((size_t)3 * 32768 * 2);
    float* pooled = (float*)p;  p += au((size_t)N_GRAPH * DIM * 4);
    float* tpre   = (float*)p;  p += au((size_t)N_GRAPH * HID * 4);
    float* vnpre  = (float*)p;  p += au((size_t)N_GRAPH * DIM * 4);
    float* statsA = (float*)p;  p += au(2048 * 4);
    float* statsB = (float*)p;  p += au(2048 * 4);
    int* rowptr = (int*)p;  p += au((size_t)(N_NODES + 1) * 4);
    int* cursor = (int*)p;  p += au((size_t)N_NODES * 4);
    int2* sE    = (int2*)p;

    const float invN = 1.0f / (float)N_NODES;
    const float invG = 1.0f / (float)N_GRAPH;
    const int total4 = N_NODES * DIM / 4;

    // ---- one-time prep ----
    hipMemsetAsync(cursor, 0, N_NODES * sizeof(int), stream);
    hipMemsetAsync(pooled, 0, (size_t)N_GRAPH * DIM * sizeof(float), stream);
    hist_kernel<<<(N_EDGES + 255) / 256, 256, 0, stream>>>(edge_index, cursor);
    scan_kernel<<<1, 1024, 0, stream>>>(cursor, rowptr);   // also re-zeroes cursor
    scatter_kernel<<<(N_EDGES + 255) / 256, 256, 0, stream>>>(edge_index, rowptr, cursor, sE);
    wconv_kernel<<<768, 256, 0, stream>>>(W1, W2, W1t, W2t);

    for (int l = 0; l < N_LAYER; ++l) {
        float* cur = (l & 1) ? statsB : statsA;
        float* prv = (l & 1) ? statsA : statsB;

        if (l == 0)
            hin_kernel<false, 0><<<(total4 + 255) / 256, 256, 0, stream>>>(
                x, nullptr, nullptr, nullptr, nullptr, 0.f, batch,
                vn_emb, nullptr, nullptr, nullptr, nullptr, nullptr, 0.f,
                h_in, total4);
        else
            hin_kernel<true, 1><<<(total4 + 255) / 256, 256, 0, stream>>>(
                outp, prv + 512, prv + 640, gb + (size_t)(l - 1) * DIM, bb + (size_t)(l - 1) * DIM,
                invN, batch,
                nullptr, vnpre, prv + 1280, prv + 1408,
                gv2 + (size_t)(l - 1) * DIM, btv2 + (size_t)(l - 1) * DIM, invG,
                h_in, total4);

        if (l < N_LAYER - 1)
            pooled_chunk_kernel<<<(N_NODES + PCHUNK - 1) / PCHUNK, 128, 0, stream>>>(
                h_in, batch, pooled);

        aggr_kernel<<<(N_NODES + 3) / 4, 256, 0, stream>>>(
            rowptr, sE, edge_attr, We + (size_t)l * EFEAT * DIM, be + (size_t)l * DIM,
            h_in, z_bf, cur);

        dim3 g1d((N_NODES + 127) / 128, HID / 128);
        gemm_bf16_kernel<0, true><<<g1d, 256, 0, stream>>>(
            z_bf, nullptr, nullptr, nullptr, nullptr, 0.f,
            W1t + (size_t)l * 32768, b1 + (size_t)l * HID,
            (void*)c1_bf, cur + 0, cur + 256, N_NODES, DIM, HID);

        dim3 g2d((N_NODES + 127) / 128, DIM / 128);
        gemm_bf16_kernel<1, false><<<g2d, 256, 0, stream>>>(
            c1_bf, cur + 0, cur + 256, g1v + (size_t)l * HID, bt1 + (size_t)l * HID, invN,
            W2t + (size_t)l * 32768, b2 + (size_t)l * DIM,
            (void*)outp, cur + 512, cur + 640, N_NODES, HID, DIM);

        if (l < N_LAYER - 1) {
            dim3 g3d(N_GRAPH / 64, HID / 64);
            if (l == 0)
                gemm_kernel<2, false><<<g3d, 256, 0, stream>>>(
                    pooled, nullptr, vn_emb,
                    nullptr, nullptr, nullptr, nullptr, 0.f,
                    Wv1 + (size_t)l * DIM * HID, bv1 + (size_t)l * HID,
                    tpre, cur + 768, cur + 1024, N_GRAPH, DIM, HID, nullptr);
            else
                gemm_kernel<3, false><<<g3d, 256, 0, stream>>>(
                    pooled, vnpre, nullptr,
                    prv + 1280, prv + 1408, gv2 + (size_t)(l - 1) * DIM, btv2 + (size_t)(l - 1) * DIM, invG,
                    Wv1 + (size_t)l * DIM * HID, bv1 + (size_t)l * HID,
                    tpre, cur + 768, cur + 1024, N_GRAPH, DIM, HID, nullptr);

            dim3 g4d(N_GRAPH / 64, DIM / 64);
            gemm_kernel<1, true><<<g4d, 256, 0, stream>>>(
                tpre, nullptr, nullptr,
                cur + 768, cur + 1024, gv1 + (size_t)l * HID, btv1 + (size_t)l * HID, invG,
                Wv2 + (size_t)l * HID * DIM, bv2 + (size_t)l * DIM,
                vnpre, cur + 1280, cur + 1408, N_GRAPH, HID, DIM, pooled);
        }
    }

    float* lastStats = statsA;   // layer 2 parity 0
    final_bn_kernel<<<(total4 + 255) / 256, 256, 0, stream>>>(
        outp, lastStats + 512, lastStats + 640, gb + (size_t)2 * DIM, bb + (size_t)2 * DIM, invN, total4);
}